// Round 9
// baseline (689.809 us; speedup 1.0000x reference)
//
#include <hip/hip_runtime.h>

#define NN 20000
#define NE 320000
#define ZD 128

typedef __attribute__((ext_vector_type(8))) short s16x8;
typedef __attribute__((ext_vector_type(16))) float f32x16;

#define MFMA32(A, B, C) __builtin_amdgcn_mfma_f32_32x32x16_bf16((A), (B), (C), 0, 0, 0)

__device__ __forceinline__ unsigned short bf16_rne(float v) {
    unsigned int u = __float_as_uint(v);
    unsigned int r = u + 0x7FFFu + ((u >> 16) & 1u);
    return (unsigned short)(r >> 16);
}
__device__ __forceinline__ float bf16f(unsigned short h) {
    return __uint_as_float(((unsigned int)h) << 16);
}

// ---------------- counting sort by dst (validated R5) ----------------

__global__ __launch_bounds__(256) void hist_kernel(const int* __restrict__ dst,
                                                   int* __restrict__ hist)
{
    const int e = blockIdx.x * 256 + threadIdx.x;
    if (e < NE) atomicAdd(&hist[dst[e]], 1);
}

__global__ __launch_bounds__(1024) void scan_kernel(const int* __restrict__ hist,
                                                    int* __restrict__ curs)
{
    __shared__ int tmp[1024];
    __shared__ int carry;
    const int t = threadIdx.x;
    if (t == 0) carry = 0;
    __syncthreads();
    for (int base = 0; base < NN; base += 1024) {
        const int i = base + t;
        const int v = (i < NN) ? hist[i] : 0;
        tmp[t] = v;
        __syncthreads();
        for (int off = 1; off < 1024; off <<= 1) {
            const int u = (t >= off) ? tmp[t - off] : 0;
            __syncthreads();
            tmp[t] += u;
            __syncthreads();
        }
        const int incl = tmp[t];
        if (i < NN) curs[i] = carry + incl - v;
        __syncthreads();
        if (t == 1023) carry += incl;
        __syncthreads();
    }
}

__global__ __launch_bounds__(256) void scatter_kernel(
    const int* __restrict__ src, const int* __restrict__ dst,
    int* __restrict__ curs,
    int* __restrict__ src_s, int* __restrict__ dst_s, int* __restrict__ perm)
{
    const int e = blockIdx.x * 256 + threadIdx.x;
    if (e < NE) {
        const int d = dst[e];
        const int p = atomicAdd(&curs[d], 1);
        src_s[p] = src[e];
        dst_s[p] = d;
        perm[p] = e;
    }
}

// ---------------- Wab = A - B (rows 0..DIN vs DIN..2DIN of Wm) ----------------

__global__ __launch_bounds__(256) void sub_w(const float* __restrict__ Wm, int din,
                                             float* __restrict__ Wab)
{
    const int i = blockIdx.x * 256 + threadIdx.x;
    if (i < din * ZD) Wab[i] = Wm[i] - Wm[(size_t)din * ZD + i];
}

// ---------------- weight packing: 32x32x16 B-fragment order (validated R7) ----------------
// W points at rows [DIN .. 3*DIN+4) of Wm (= [B; C; E], contiguous), K = 2*DIN+4.

__global__ __launch_bounds__(256) void pack_w(const float* __restrict__ W, int K, int total,
                                              unsigned short* __restrict__ Bh,
                                              unsigned short* __restrict__ Bl)
{
    const int f = blockIdx.x * 256 + threadIdx.x;
    if (f >= total) return;
    const int lane = f & 63;
    const int ct = (f >> 6) & 3;
    const int ks = f >> 8;
    const int k0 = ks * 16 + (lane >> 5) * 8;
    const int col = ct * 32 + (lane & 31);
    unsigned short* oh = Bh + (size_t)f * 8;
    unsigned short* ol = Bl + (size_t)f * 8;
    #pragma unroll
    for (int i = 0; i < 8; ++i) {
        const int k = k0 + i;
        const float v = (k < K) ? W[(size_t)k * ZD + col] : 0.f;
        const unsigned short h = bf16_rne(v);
        oh[i] = h;
        ol[i] = bf16_rne(v - bf16f(h));
    }
}

// ---------------- MFMA 32x32x16 split-bf16 edge GEMM over [x_j | x_i*x_j | ea] ----------------
// msg = relu(P[dst] + GEMM + bias); P = x @ (A - B) precomputed fp32.

template<int DIN>
__global__ __launch_bounds__(256, 4) void edge_msg_had(
    const float* __restrict__ x,
    const int* __restrict__ src_s,
    const int* __restrict__ dst_s,   // sorted
    const int* __restrict__ perm,
    const float4* __restrict__ ea,
    const unsigned short* __restrict__ Bh,
    const unsigned short* __restrict__ Bl,
    const float* __restrict__ bm,
    const float* __restrict__ P,     // [NN,128] fp32
    float* __restrict__ agg)
{
    constexpr int HSLAB = DIN / 64;
    constexpr int NSLAB = 2 * HSLAB;
    __shared__ unsigned short fsh[64][64];
    __shared__ unsigned short fsl[64][64];
    __shared__ int dsh[64];
    const int t = threadIdx.x;
    const int e0 = blockIdx.x * 64;
    const int lane = t & 63;
    const int w = t >> 6;

    f32x16 acc0 = {0,0,0,0,0,0,0,0,0,0,0,0,0,0,0,0};
    f32x16 acc1 = {0,0,0,0,0,0,0,0,0,0,0,0,0,0,0,0};

    if (t < 64) dsh[t] = dst_s[e0 + t];

    const int cl = lane & 31;
    const int g2 = lane >> 5;
    const int ar0 = cl;
    const int ar1 = 32 + cl;
    char* const fshB = (char*)fsh;
    char* const fslB = (char*)fsl;

    const int sc = (t & 15) * 8;
    const int sr0 = t >> 4;

    for (int s = 0; s < NSLAB; ++s) {
        const bool had = (s >= HSLAB);
        const int col0 = (had ? (s - HSLAB) : s) * 64;
        #pragma unroll
        for (int p = 0; p < 4; ++p) {
            const int r = sr0 + p * 16;
            const int e = e0 + r;
            const float4 xj = *(const float4*)&x[(size_t)src_s[e] * DIN + col0 + sc / 2];
            float4 v;
            if (!had) {
                v = xj;
            } else {
                const float4 xi = *(const float4*)&x[(size_t)dst_s[e] * DIN + col0 + sc / 2];
                v = make_float4(xj.x * xi.x, xj.y * xi.y, xj.z * xi.z, xj.w * xi.w);
            }
            const float vv[4] = {v.x, v.y, v.z, v.w};
            unsigned int hp[2], lp[2];
            #pragma unroll
            for (int q = 0; q < 2; ++q) {
                const unsigned short h0 = bf16_rne(vv[2*q]);
                const unsigned short h1 = bf16_rne(vv[2*q+1]);
                const unsigned short l0 = bf16_rne(vv[2*q]   - bf16f(h0));
                const unsigned short l1 = bf16_rne(vv[2*q+1] - bf16f(h1));
                hp[q] = (unsigned int)h0 | ((unsigned int)h1 << 16);
                lp[q] = (unsigned int)l0 | ((unsigned int)l1 << 16);
            }
            const int off = r * 128 + (sc ^ ((r & 7) << 4));
            *(uint2*)(fshB + off) = make_uint2(hp[0], hp[1]);
            *(uint2*)(fslB + off) = make_uint2(lp[0], lp[1]);
        }
        __syncthreads();
        #pragma unroll
        for (int kl = 0; kl < 4; ++kl) {
            const int ks = s * 4 + kl;
            const int kb = kl * 32 + g2 * 16;
            const s16x8 ah0 = *(const s16x8*)(fshB + ar0 * 128 + (kb ^ ((ar0 & 7) << 4)));
            const s16x8 al0 = *(const s16x8*)(fslB + ar0 * 128 + (kb ^ ((ar0 & 7) << 4)));
            const s16x8 ah1 = *(const s16x8*)(fshB + ar1 * 128 + (kb ^ ((ar1 & 7) << 4)));
            const s16x8 al1 = *(const s16x8*)(fslB + ar1 * 128 + (kb ^ ((ar1 & 7) << 4)));
            const unsigned short* bp = Bh + ((size_t)(ks * 4 + w) * 64 + lane) * 8;
            const unsigned short* lp = Bl + ((size_t)(ks * 4 + w) * 64 + lane) * 8;
            const s16x8 bh = *(const s16x8*)bp;
            const s16x8 bl = *(const s16x8*)lp;
            acc0 = MFMA32(al0, bh, acc0);
            acc0 = MFMA32(ah0, bl, acc0);
            acc0 = MFMA32(ah0, bh, acc0);
            acc1 = MFMA32(al1, bh, acc1);
            acc1 = MFMA32(ah1, bl, acc1);
            acc1 = MFMA32(ah1, bh, acc1);
        }
        __syncthreads();
    }

    {   // tail: ea (4 real k + 12 zero), single K-step of 16
        const int r = t >> 2, q = t & 3;
        uint2 hw = make_uint2(0, 0), lw = make_uint2(0, 0);
        if (q == 0) {
            const float4 a = ea[perm[e0 + r]];
            const float vv[4] = {a.x, a.y, a.z, a.w};
            unsigned int hp[2], lp[2];
            #pragma unroll
            for (int qq = 0; qq < 2; ++qq) {
                const unsigned short h0 = bf16_rne(vv[2*qq]);
                const unsigned short h1 = bf16_rne(vv[2*qq+1]);
                const unsigned short l0 = bf16_rne(vv[2*qq]   - bf16f(h0));
                const unsigned short l1 = bf16_rne(vv[2*qq+1] - bf16f(h1));
                hp[qq] = (unsigned int)h0 | ((unsigned int)h1 << 16);
                lp[qq] = (unsigned int)l0 | ((unsigned int)l1 << 16);
            }
            hw = make_uint2(hp[0], hp[1]);
            lw = make_uint2(lp[0], lp[1]);
        }
        const int off = r * 128 + ((q * 8) ^ ((r & 7) << 4));
        *(uint2*)(fshB + off) = hw;
        *(uint2*)(fslB + off) = lw;
        __syncthreads();
        const int ks = NSLAB * 4;
        const int kb = g2 * 16;
        const s16x8 ah0 = *(const s16x8*)(fshB + ar0 * 128 + (kb ^ ((ar0 & 7) << 4)));
        const s16x8 al0 = *(const s16x8*)(fslB + ar0 * 128 + (kb ^ ((ar0 & 7) << 4)));
        const s16x8 ah1 = *(const s16x8*)(fshB + ar1 * 128 + (kb ^ ((ar1 & 7) << 4)));
        const s16x8 al1 = *(const s16x8*)(fslB + ar1 * 128 + (kb ^ ((ar1 & 7) << 4)));
        const unsigned short* bp = Bh + ((size_t)(ks * 4 + w) * 64 + lane) * 8;
        const unsigned short* lp2 = Bl + ((size_t)(ks * 4 + w) * 64 + lane) * 8;
        const s16x8 bh = *(const s16x8*)bp;
        const s16x8 bl = *(const s16x8*)lp2;
        acc0 = MFMA32(al0, bh, acc0);
        acc0 = MFMA32(ah0, bl, acc0);
        acc0 = MFMA32(ah0, bh, acc0);
        acc1 = MFMA32(al1, bh, acc1);
        acc1 = MFMA32(ah1, bl, acc1);
        acc1 = MFMA32(ah1, bh, acc1);
    }

    // ---- bias + P[dst] + relu + run-reduced atomic scatter ----
    const int col = w * 32 + cl;
    const float bias = bm[col];
    int cur = -1;
    float sum = 0.f;
    #pragma unroll
    for (int rt = 0; rt < 2; ++rt) {
        #pragma unroll
        for (int reg = 0; reg < 16; ++reg) {
            const int row = rt * 32 + (reg & 3) + 8 * (reg >> 2) + 4 * g2;
            const int d = dsh[row];
            const float pv = P[(size_t)d * ZD + col];
            const float v = fmaxf((rt == 0 ? acc0[reg] : acc1[reg]) + bias + pv, 0.f);
            if (d == cur) {
                sum += v;
            } else {
                if (cur >= 0) atomicAdd(&agg[(size_t)cur * ZD + col], sum);
                cur = d;
                sum = v;
            }
        }
    }
    atomicAdd(&agg[(size_t)cur * ZD + col], sum);
}

// ---------------- fp32 4-row GEMM helper (validated R8) ----------------

#define ACC4_STEP(A, W) \
    acc[i][0] = fmaf((A), (W).x, acc[i][0]); \
    acc[i][1] = fmaf((A), (W).y, acc[i][1]); \
    acc[i][2] = fmaf((A), (W).z, acc[i][2]); \
    acc[i][3] = fmaf((A), (W).w, acc[i][3]);

template<int K>
__device__ __forceinline__ void gemm_acc4(const float* __restrict__ fs,  // [32][K]
                                          const float* __restrict__ W,
                                          int zc, int er, float (&acc)[4][4])
{
    #pragma unroll 2
    for (int k = 0; k < K; k += 4) {
        const float* wr = W + (size_t)k * ZD + zc;
        const float4 w0 = *(const float4*)(wr);
        const float4 w1 = *(const float4*)(wr + ZD);
        const float4 w2 = *(const float4*)(wr + 2 * ZD);
        const float4 w3 = *(const float4*)(wr + 3 * ZD);
        #pragma unroll
        for (int i = 0; i < 4; ++i) {
            const float4 a = *(const float4*)&fs[(er + i) * K + k];
            ACC4_STEP(a.x, w0)
            ACC4_STEP(a.y, w1)
            ACC4_STEP(a.z, w2)
            ACC4_STEP(a.w, w3)
        }
    }
}

// ---------------- standalone P = xin @ W (no bias/relu), 32-row tiles ----------------

template<int DIN>
__global__ __launch_bounds__(256, 4) void node_gemm(
    const float* __restrict__ xin,
    const float* __restrict__ W,     // [DIN,128]
    float* __restrict__ outp)
{
    __shared__ float fs[32 * DIN];
    const int t  = threadIdx.x;
    const int n0 = blockIdx.x * 32;

    constexpr int CPR = DIN / 4;
    constexpr int LX = 32 * CPR / 256;
    #pragma unroll
    for (int p = 0; p < LX; ++p) {
        const int f = t + 256 * p;
        const int r = f / CPR, c = f % CPR;
        *(float4*)&fs[r * DIN + c * 4] = *(const float4*)&xin[(size_t)(n0 + r) * DIN + c * 4];
    }
    __syncthreads();

    const int zc = (t & 31) * 4;
    const int er = (t >> 5) * 4;
    float acc[4][4] = {};
    gemm_acc4<DIN>(fs, W, zc, er, acc);

    #pragma unroll
    for (int i = 0; i < 4; ++i) {
        *(float4*)&outp[(size_t)(n0 + er + i) * ZD + zc] =
            make_float4(acc[i][0], acc[i][1], acc[i][2], acc[i][3]);
    }
}

// ---------------- node MLP (validated R8) + fused next-conv P GEMM ----------------

template<int DIN>
__global__ __launch_bounds__(256, 4) void node_mlp32(
    const float* __restrict__ xin,
    const float* __restrict__ agg,
    const int* __restrict__ deg,
    const float* __restrict__ Wf,
    const float* __restrict__ bf,
    float* __restrict__ xout,
    const float* __restrict__ Wab_next,  // [128,128] or null
    float* __restrict__ Pout)
{
    constexpr int K = DIN + 128;
    __shared__ float fs[32 * K];
    const int t  = threadIdx.x;
    const int n0 = blockIdx.x * 32;

    {
        constexpr int CPR = DIN / 4;
        constexpr int LX = 32 * CPR / 256;
        #pragma unroll
        for (int p = 0; p < LX; ++p) {
            const int f = t + 256 * p;
            const int r = f / CPR, c = f % CPR;
            *(float4*)&fs[r * K + c * 4] = *(const float4*)&xin[(size_t)(n0 + r) * DIN + c * 4];
        }
    }
    {
        #pragma unroll
        for (int p = 0; p < 4; ++p) {
            const int f = t + 256 * p;
            const int r = f >> 5, c = f & 31;
            const float inv = 1.0f / fmaxf((float)deg[n0 + r], 1.0f);
            const float4 a = *(const float4*)&agg[(size_t)(n0 + r) * ZD + c * 4];
            *(float4*)&fs[r * K + DIN + c * 4] =
                make_float4(a.x * inv, a.y * inv, a.z * inv, a.w * inv);
        }
    }
    __syncthreads();

    const int zc = (t & 31) * 4;
    const int er = (t >> 5) * 4;
    float acc[4][4] = {};
    gemm_acc4<K>(fs, Wf, zc, er, acc);

    const float4 b = *(const float4*)&bf[zc];
    float4 o[4];
    #pragma unroll
    for (int i = 0; i < 4; ++i) {
        o[i].x = fmaxf(acc[i][0] + b.x, 0.f);
        o[i].y = fmaxf(acc[i][1] + b.y, 0.f);
        o[i].z = fmaxf(acc[i][2] + b.z, 0.f);
        o[i].w = fmaxf(acc[i][3] + b.w, 0.f);
        *(float4*)&xout[(size_t)(n0 + er + i) * ZD + zc] = o[i];
    }

    if (Wab_next) {   // P_next = relu-out @ Wab_next (out tile is on-chip)
        __syncthreads();
        #pragma unroll
        for (int i = 0; i < 4; ++i)
            *(float4*)&fs[(er + i) * 128 + zc] = o[i];
        __syncthreads();
        float accp[4][4] = {};
        gemm_acc4<128>(fs, Wab_next, zc, er, accp);
        #pragma unroll
        for (int i = 0; i < 4; ++i) {
            *(float4*)&Pout[(size_t)(n0 + er + i) * ZD + zc] =
                make_float4(accp[i][0], accp[i][1], accp[i][2], accp[i][3]);
        }
    }
}

// ---------------- fusion (validated R8) ----------------

__global__ __launch_bounds__(256, 3) void fusion32(
    const float* __restrict__ x1,
    const float* __restrict__ x2,
    const float* __restrict__ x3,
    const float* __restrict__ Wl,
    const float* __restrict__ bl,
    float* __restrict__ out)
{
    constexpr int K = 384;
    __shared__ float fs[32 * K];
    const int t  = threadIdx.x;
    const int n0 = blockIdx.x * 32;

    #pragma unroll
    for (int p = 0; p < 4; ++p) {
        const int f = t + 256 * p;
        const int r = f >> 5, c = f & 31;
        *(float4*)&fs[r * K + c * 4] = *(const float4*)&x1[(size_t)(n0 + r) * ZD + c * 4];
    }
    #pragma unroll
    for (int p = 0; p < 4; ++p) {
        const int f = t + 256 * p;
        const int r = f >> 5, c = f & 31;
        *(float4*)&fs[r * K + 128 + c * 4] = *(const float4*)&x2[(size_t)(n0 + r) * ZD + c * 4];
    }
    #pragma unroll
    for (int p = 0; p < 4; ++p) {
        const int f = t + 256 * p;
        const int r = f >> 5, c = f & 31;
        *(float4*)&fs[r * K + 256 + c * 4] = *(const float4*)&x3[(size_t)(n0 + r) * ZD + c * 4];
    }
    __syncthreads();

    const int zc = (t & 31) * 4;
    const int er = (t >> 5) * 4;
    float acc[4][4] = {};
    gemm_acc4<K>(fs, Wl, zc, er, acc);

    const float4 b = *(const float4*)&bl[zc];
    #pragma unroll
    for (int i = 0; i < 4; ++i) {
        float4 o;
        o.x = fmaxf(acc[i][0] + b.x, 0.f);
        o.y = fmaxf(acc[i][1] + b.y, 0.f);
        o.z = fmaxf(acc[i][2] + b.z, 0.f);
        o.w = fmaxf(acc[i][3] + b.w, 0.f);
        *(float4*)&out[(size_t)(n0 + er + i) * ZD + zc] = o;
    }
}

extern "C" void kernel_launch(void* const* d_in, const int* in_sizes, int n_in,
                              void* d_out, int out_size, void* d_ws, size_t ws_size,
                              hipStream_t stream)
{
    (void)in_sizes; (void)n_in; (void)out_size; (void)ws_size;

    const float* x   = (const float*)d_in[0];
    const int*   ei  = (const int*)d_in[1];
    const float* ea  = (const float*)d_in[2];
    const float* Wm1 = (const float*)d_in[3];  const float* bm1 = (const float*)d_in[4];
    const float* Wf1 = (const float*)d_in[5];  const float* bf1 = (const float*)d_in[6];
    const float* Wm2 = (const float*)d_in[7];  const float* bm2 = (const float*)d_in[8];
    const float* Wf2 = (const float*)d_in[9];  const float* bf2 = (const float*)d_in[10];
    const float* Wm3 = (const float*)d_in[11]; const float* bm3 = (const float*)d_in[12];
    const float* Wf3 = (const float*)d_in[13]; const float* bf3 = (const float*)d_in[14];
    const float* Wl  = (const float*)d_in[15]; const float* bl  = (const float*)d_in[16];

    const int* src = ei;
    const int* dst = ei + NE;

    // ws (~45.6 MB): agg | x1 | x2 | P | hist | curs | src_s | dst_s | perm | Wab1..3 | packed B
    float* agg  = (float*)d_ws;
    float* x1   = agg + (size_t)NN * ZD;
    float* x2   = x1  + (size_t)NN * ZD;
    float* P    = x2  + (size_t)NN * ZD;
    int*   hist = (int*)(P + (size_t)NN * ZD);
    int*   curs = hist + 20480;
    int*   src_s = curs + 20480;
    int*   dst_s = src_s + NE;
    int*   perm  = dst_s + NE;
    float* Wab1 = (float*)(perm + NE);           // 64*128
    float* Wab2 = Wab1 + 64 * ZD;                // 128*128
    float* Wab3 = Wab2 + 128 * ZD;
    // packed weights (32x32x16): conv1 Kpad=144 -> 9 ks, conv2/3 Kpad=272 -> 17 ks
    const int F1 = 9 * 4 * 64, F2 = 17 * 4 * 64;
    unsigned short* B1h = (unsigned short*)(Wab3 + 128 * ZD);
    unsigned short* B1l = B1h + (size_t)F1 * 8;
    unsigned short* B2h = B1l + (size_t)F1 * 8;
    unsigned short* B2l = B2h + (size_t)F2 * 8;
    unsigned short* B3h = B2l + (size_t)F2 * 8;
    unsigned short* B3l = B3h + (size_t)F2 * 8;
    float* x3   = (float*)d_out;
    float* out  = (float*)d_out;

    const size_t aggBytes = (size_t)NN * ZD * sizeof(float);

    // ---- sort + weight prep ----
    hipMemsetAsync(hist, 0, 20480 * sizeof(int), stream);
    hist_kernel<<<(NE + 255) / 256, 256, 0, stream>>>(dst, hist);
    scan_kernel<<<1, 1024, 0, stream>>>(hist, curs);
    scatter_kernel<<<(NE + 255) / 256, 256, 0, stream>>>(src, dst, curs, src_s, dst_s, perm);
    sub_w<<<(64 * ZD + 255) / 256, 256, 0, stream>>>(Wm1, 64, Wab1);
    sub_w<<<(128 * ZD + 255) / 256, 256, 0, stream>>>(Wm2, 128, Wab2);
    sub_w<<<(128 * ZD + 255) / 256, 256, 0, stream>>>(Wm3, 128, Wab3);
    pack_w<<<(F1 + 255) / 256, 256, 0, stream>>>(Wm1 + 64 * ZD, 132, F1, B1h, B1l);
    pack_w<<<(F2 + 255) / 256, 256, 0, stream>>>(Wm2 + 128 * ZD, 260, F2, B2h, B2l);
    pack_w<<<(F2 + 255) / 256, 256, 0, stream>>>(Wm3 + 128 * ZD, 260, F2, B3h, B3l);

    const int EG = NE / 64;        // 5000
    const int NG32 = NN / 32;      // 625 exact

    // conv1  (P1 = x @ Wab1)
    node_gemm<64><<<NG32, 256, 0, stream>>>(x, Wab1, P);
    hipMemsetAsync(agg, 0, aggBytes, stream);
    edge_msg_had<64><<<EG, 256, 0, stream>>>(x, src_s, dst_s, perm, (const float4*)ea,
                                             B1h, B1l, bm1, P, agg);
    node_mlp32<64><<<NG32, 256, 0, stream>>>(x, agg, hist, Wf1, bf1, x1, Wab2, P);  // P2

    // conv2
    hipMemsetAsync(agg, 0, aggBytes, stream);
    edge_msg_had<128><<<EG, 256, 0, stream>>>(x1, src_s, dst_s, perm, (const float4*)ea,
                                              B2h, B2l, bm2, P, agg);
    node_mlp32<128><<<NG32, 256, 0, stream>>>(x1, agg, hist, Wf2, bf2, x2, Wab3, P); // P3

    // conv3
    hipMemsetAsync(agg, 0, aggBytes, stream);
    edge_msg_had<128><<<EG, 256, 0, stream>>>(x2, src_s, dst_s, perm, (const float4*)ea,
                                              B3h, B3l, bm3, P, agg);
    node_mlp32<128><<<NG32, 256, 0, stream>>>(x2, agg, hist, Wf3, bf3, x3, nullptr, nullptr);

    // fusion
    fusion32<<<NG32, 256, 0, stream>>>(x1, x2, x3, Wl, bl, out);
}